// Round 1
// baseline (396.161 us; speedup 1.0000x reference)
//
#include <hip/hip_runtime.h>

// Lukasiewicz t-norm feature expansion.
//   out[:, 0:16]    = x
//   out[:, 16:136]  = max(x[a]+x[b] - 1, 0)          (a,b)   lex combos of 16
//   out[:, 136:696] = max((x[a]+x[b]) + x[c] - 2, 0) (a,b,c) lex combos of 16
//
// R3 design: factor pair sums. Phase A computes all 120 raw pair sums per row
// once into LDS (and emits the pair block), phase C consumes them so each
// triple is 2 LDS reads + add + add(-2) + max (exact association preserved:
// ((xa+xb)+xc)-2 matches jnp.sum order -> absmax 0).
// R2 (3 reads + bias-decode per element, 54 VALU/quad) measured 366.7 us
// total; rocprof showed the kernel dispatch itself < 227 us (below the
// harness 1.46 GB poison fills at 6.4 TB/s), i.e. NOT at the 59 us write
// roofline -> issue-side (LDS/VALU) bound, hence this op-count cut.

#define NCOLS 696
#define RPT   16          // rows per tile
#define RSTR  140         // per-row LDS floats: [0..15]=x, [16..135]=raw pair sums, pad 4
#define PQ    30          // pair quads per row   (120/4)
#define TQ    140         // triple quads per row (560/4)

typedef float v4f __attribute__((ext_vector_type(4)));

struct alignas(16) TripTab { unsigned short v[560]; };
struct alignas(16) PairTab { unsigned short v[120]; };

// triple descriptor: (16 + pairIdx(a,b)) in bits [7:0], c in bits [11:8]
constexpr TripTab make_ttab() {
    TripTab t{};
    int pidx[16][16] = {};
    int pi = 0;
    for (int a = 0; a < 16; ++a)
        for (int b = a + 1; b < 16; ++b)
            pidx[a][b] = pi++;
    int k = 0;
    for (int a = 0; a < 16; ++a)
        for (int b = a + 1; b < 16; ++b)
            for (int c = b + 1; c < 16; ++c)
                t.v[k++] = (unsigned short)((16 + pidx[a][b]) | (c << 8));
    return t;
}
// pair descriptor: a in [4:0], b in [9:5], lex order
constexpr PairTab make_ptab() {
    PairTab t{};
    int k = 0;
    for (int a = 0; a < 16; ++a)
        for (int b = a + 1; b < 16; ++b)
            t.v[k++] = (unsigned short)(a | (b << 5));
    return t;
}

__constant__ TripTab g_ttab = make_ttab();
__constant__ PairTab g_ptab = make_ptab();

__global__ __launch_bounds__(256) void luk_kernel(const float* __restrict__ x,
                                                  float* __restrict__ out,
                                                  int nrows, int ntiles) {
    // 16 rows x 140 floats = 8960 B LDS; row stride 560 B is 16B-aligned so
    // pair-sum quads can be ds_write_b128 / ds_read_b128.
    __shared__ float L[RPT * RSTR];
    const int t = threadIdx.x;
    const ushort4* __restrict__ tt4 = reinterpret_cast<const ushort4*>(g_ttab.v);
    const ushort4* __restrict__ pt4 = reinterpret_cast<const ushort4*>(g_ptab.v);

    for (int tile = blockIdx.x; tile < ntiles; tile += gridDim.x) {
        const int row0 = tile * RPT;
        const int rlim = min(RPT, nrows - row0);
        const size_t obase = (size_t)row0 * NCOLS;

        {   // stage x: 256 consecutive floats, coalesced
            const int r = t >> 4, a = t & 15;
            float v = 0.0f;
            if (r < rlim) v = x[(size_t)row0 * 16 + t];
            L[r * RSTR + a] = v;
        }
        __syncthreads();

        // ---- phase A: pairs. Emit out[:,16..136) and stash raw sums in LDS.
        for (int i = t; i < rlim * PQ; i += 256) {
            const int r = (unsigned)i / (unsigned)PQ;
            const int q = i - r * PQ;
            const ushort4 pv = pt4[q];
            const float* __restrict__ xr = &L[r * RSTR];
            const float s0 = xr[pv.x & 31] + xr[pv.x >> 5];
            const float s1 = xr[pv.y & 31] + xr[pv.y >> 5];
            const float s2 = xr[pv.z & 31] + xr[pv.z >> 5];
            const float s3 = xr[pv.w & 31] + xr[pv.w >> 5];
            v4f sv; sv.x = s0; sv.y = s1; sv.z = s2; sv.w = s3;
            *reinterpret_cast<v4f*>(&L[r * RSTR + 16 + 4 * q]) = sv;  // raw sums
            v4f o;
            o.x = fmaxf(s0 - 1.0f, 0.0f);
            o.y = fmaxf(s1 - 1.0f, 0.0f);
            o.z = fmaxf(s2 - 1.0f, 0.0f);
            o.w = fmaxf(s3 - 1.0f, 0.0f);
            __builtin_nontemporal_store(
                o, reinterpret_cast<v4f*>(out + obase + (size_t)r * NCOLS + 16) + q);
        }

        // ---- phase B: singles. out[:,0..16) = x (64 quads).
        if (t < rlim * 4) {
            const int r = t >> 2, q = t & 3;
            const v4f o = *reinterpret_cast<const v4f*>(&L[r * RSTR + 4 * q]);
            __builtin_nontemporal_store(
                o, reinterpret_cast<v4f*>(out + obase + (size_t)r * NCOLS) + q);
        }
        __syncthreads();   // pair sums visible

        // ---- phase C: triples. out[:,136..696) = max((ps + xc) - 2, 0).
        const int nq = rlim * TQ;
        for (int i = t; i < nq; i += 256) {
            const int r = (unsigned)i / (unsigned)TQ;
            const int q = i - r * TQ;
            const ushort4 tv = tt4[q];
            const float* __restrict__ xr = &L[r * RSTR];
            v4f o;
            o.x = fmaxf(xr[tv.x & 255] + xr[tv.x >> 8] - 2.0f, 0.0f);
            o.y = fmaxf(xr[tv.y & 255] + xr[tv.y >> 8] - 2.0f, 0.0f);
            o.z = fmaxf(xr[tv.z & 255] + xr[tv.z >> 8] - 2.0f, 0.0f);
            o.w = fmaxf(xr[tv.w & 255] + xr[tv.w >> 8] - 2.0f, 0.0f);
            __builtin_nontemporal_store(
                o, reinterpret_cast<v4f*>(out + obase + (size_t)r * NCOLS + 136) + q);
        }
        __syncthreads();   // L reused next tile
    }
}

extern "C" void kernel_launch(void* const* d_in, const int* in_sizes, int n_in,
                              void* d_out, int out_size, void* d_ws, size_t ws_size,
                              hipStream_t stream) {
    const float* x = (const float*)d_in[0];
    float* out = (float*)d_out;
    const int nrows  = in_sizes[0] / 16;            // 131072
    const int ntiles = (nrows + RPT - 1) / RPT;     // 8192
    const int blocks = ntiles < 2048 ? ntiles : 2048;  // 8 blocks/CU resident
    luk_kernel<<<blocks, 256, 0, stream>>>(x, out, nrows, ntiles);
}